// Round 6
// baseline (43223.428 us; speedup 1.0000x reference)
//
#include <hip/hip_runtime.h>
#include <hip/hip_bf16.h>
#include <math.h>

#define N_WORDS 8192
#define LMAX    16
#define WED     506
#define WHD     512
#define CED     6
#define CHD     6
#define CVOC    128
#define TAG     64
#define XDIM    512      // WED + CHD
#define G4      2048     // 4*WHD
#define NBLK    256      // launched blocks for word LSTM (1/CU, co-resident)
#define NROLE   32       // role WGs, all guaranteed on one XCD

__device__ __forceinline__ float fast_sigmoid(float x) { return 1.0f / (1.0f + __expf(-x)); }
__device__ __forceinline__ float fast_tanh(float x)    { return 2.0f / (1.0f + __expf(-2.0f * x)) - 1.0f; }

__device__ __forceinline__ float q_lo(unsigned long long q) {
    return __uint_as_float((unsigned)(q & 0xffffffffu));
}
__device__ __forceinline__ float q_hi(unsigned long long q) {
    return __uint_as_float((unsigned)(q >> 32));
}

// ---------------- Kernel A: char-level LSTM, one thread per word ----------------
__global__ void __launch_bounds__(256) char_lstm_kernel(
    const int*   __restrict__ chars,     // [N, LMAX]
    const int*   __restrict__ lens,      // [N]
    const float* __restrict__ char_emb,  // [CVOC, CED]
    const float* __restrict__ cWih,      // [24, 6]
    const float* __restrict__ cWhh,      // [24, 6]
    const float* __restrict__ cb,        // [24]
    float*       __restrict__ h_char)    // [N, CHD]
{
    __shared__ float sWih[24][6], sWhh[24][6], sb[24], semb[CVOC][CED];
    int t = threadIdx.x;
    if (t < 144) { sWih[t / 6][t % 6] = cWih[t]; sWhh[t / 6][t % 6] = cWhh[t]; }
    if (t < 24) sb[t] = cb[t];
    for (int i = t; i < CVOC * CED; i += 256) semb[i / CED][i % CED] = char_emb[i];
    __syncthreads();

    int n = blockIdx.x * 256 + t;
    if (n >= N_WORDS) return;
    int len = lens[n];
    float h[CHD] = {0, 0, 0, 0, 0, 0};
    float c[CHD] = {0, 0, 0, 0, 0, 0};
    for (int l = 0; l < LMAX; ++l) {
        if (l >= len) break;  // once l >= len no further state updates occur
        int ch = chars[n * LMAX + l];
        float e[CED];
        #pragma unroll
        for (int k = 0; k < CED; ++k) e[k] = semb[ch][k];
        float pre[24];
        #pragma unroll
        for (int g = 0; g < 24; ++g) {
            float a = sb[g];
            #pragma unroll
            for (int k = 0; k < CED; ++k) a += e[k] * sWih[g][k];
            #pragma unroll
            for (int k = 0; k < CHD; ++k) a += h[k] * sWhh[g][k];
            pre[g] = a;
        }
        #pragma unroll
        for (int u = 0; u < CHD; ++u) {
            float ig = fast_sigmoid(pre[u]);
            float fg = fast_sigmoid(pre[6 + u]);
            float gg = fast_tanh(pre[12 + u]);
            float og = fast_sigmoid(pre[18 + u]);
            float cn = fg * c[u] + ig * gg;
            c[u] = cn;
            h[u] = og * fast_tanh(cn);
        }
    }
    for (int u = 0; u < CHD; ++u) h_char[n * CHD + u] = h[u];
}

// ---------------- Kernel B0: X = [word_emb gather | h_char] ----------------
__global__ void __launch_bounds__(256) build_x_kernel(
    const int*   __restrict__ words,
    const float* __restrict__ word_emb,  // [WV, WED]
    const float* __restrict__ h_char,    // [N, CHD]
    float*       __restrict__ X)         // [N, XDIM]
{
    long idx = (long)blockIdx.x * 256 + threadIdx.x;
    if (idx >= (long)N_WORDS * XDIM) return;
    int n = (int)(idx >> 9), k = (int)(idx & 511);
    float v;
    if (k < WED) v = word_emb[(long)words[n] * WED + k];
    else         v = h_char[n * CHD + (k - WED)];
    X[idx] = v;
}

// ---------------- Kernel B1: XP4 = X @ Wih^T + b, fp32 tiled GEMM ----------------
// Epilogue writes gate-interleaved layout XP4[t][unit][gate] so the word LSTM
// reads one float4 per thread per step.
#define BM 64
#define BN 64
#define BK 16
__global__ void __launch_bounds__(256) xp_gemm_kernel(
    const float* __restrict__ X,    // [N, 512]
    const float* __restrict__ Wih,  // [2048, 512]
    const float* __restrict__ wb,   // [2048]
    float*       __restrict__ XP4)  // [N, 512, 4]
{
    __shared__ float As[BM][BK + 1];
    __shared__ float Bs[BN][BK + 1];
    int tid = threadIdx.x;
    int bm = (blockIdx.x % (N_WORDS / BM)) * BM;
    int bn = (blockIdx.x / (N_WORDS / BM)) * BN;
    int ty = tid / 16, tx = tid % 16;
    float acc[4][4] = {};
    for (int k0 = 0; k0 < XDIM; k0 += BK) {
        #pragma unroll
        for (int i = 0; i < 4; ++i) {
            int e = tid + i * 256;
            int r = e >> 4, cc = e & 15;
            As[r][cc] = X[(long)(bm + r) * XDIM + k0 + cc];
            Bs[r][cc] = Wih[(long)(bn + r) * XDIM + k0 + cc];
        }
        __syncthreads();
        #pragma unroll
        for (int kk = 0; kk < BK; ++kk) {
            float a[4], b[4];
            #pragma unroll
            for (int i = 0; i < 4; ++i) a[i] = As[ty * 4 + i][kk];
            #pragma unroll
            for (int j = 0; j < 4; ++j) b[j] = Bs[tx * 4 + j][kk];
            #pragma unroll
            for (int i = 0; i < 4; ++i)
                #pragma unroll
                for (int j = 0; j < 4; ++j) acc[i][j] += a[i] * b[j];
        }
        __syncthreads();
    }
    #pragma unroll
    for (int i = 0; i < 4; ++i) {
        int m = bm + ty * 4 + i;
        #pragma unroll
        for (int j = 0; j < 4; ++j) {
            int g = bn + tx * 4 + j;
            int unit = g & 511, gate = g >> 9;
            XP4[((long)m * WHD + unit) * 4 + gate] = acc[i][j] + wb[g];
        }
    }
}

// ---------------- Kernel C: sequential word LSTM, single-XCD L2 exchange ----------
// Launch 256 blocks x 512 threads (1 block/CU -> all co-resident, so an atomic
// arrival barrier is safe). Election: each block reads its hardware XCC_ID
// (placement ground truth, not a heuristic), publishes to per-XCD counters,
// waits for all 256 arrivals, then all blocks deterministically pick the
// max-count XCD (pigeonhole: >=32 blocks there). Blocks on the home XCD claim
// roles 0..31; everyone else exits. All 32 role WGs therefore SHARE ONE L2.
//
// Transport: producers store h+2.0 with sc0 (write-through L1 into the home L2
// -> fast path) AND sc1 from a second lane (LLC copy: insurance + later kernels).
// Pollers use sc0-only loads (L1-bypass, L2-served, ~200cy) with every-8th-round
// agent-scope loads (the R0-proven path) as an unconditional forward-progress
// guarantee. Sentinel protocol, LDS broadcast, and barrier placement are
// bit-for-bit R0: HS pre-zeroed, value h+2.0 in [1,3], ready <=> v > 0.5.
//
// Per-WG geometry: role owns units [role*16, role*16+16). 512 threads,
// ug = tid>>5 (16 units), p = tid&31; per-thread inner loop identical to R0
// (w[4][16], h16[16], 5-step shfl_xor reduce).
__global__ void __launch_bounds__(512, 1) word_lstm_kernel(
    const float* __restrict__ Whh,  // [2048, 512]
    const float* __restrict__ XP4,  // [N, 512, 4] gate-interleaved
    float*       HS,                // [N, 512]; stores h+2.0; pre-zeroed
    unsigned*    CTL)               // [16] control: [0]=arrived [1..8]=cnt [9]=claims
{
    __shared__ float hbuf[WHD];     // h[t-1] (offset removed)
    __shared__ int s_role;

    const int tid = threadIdx.x;

    // ---------------- election (one-time, ~µs) ----------------
    if (tid == 0) {
        unsigned xcc;
        asm volatile("s_getreg_b32 %0, hwreg(HW_REG_XCC_ID)" : "=s"(xcc));
        xcc &= 7u;
        __hip_atomic_fetch_add(&CTL[1 + xcc], 1u, __ATOMIC_RELAXED, __HIP_MEMORY_SCOPE_AGENT);
        __hip_atomic_fetch_add(&CTL[0], 1u, __ATOMIC_RELAXED, __HIP_MEMORY_SCOPE_AGENT);
        while (__hip_atomic_load(&CTL[0], __ATOMIC_RELAXED, __HIP_MEMORY_SCOPE_AGENT) < NBLK)
            __builtin_amdgcn_s_sleep(1);
        unsigned best = 0, bc = 0;
        for (int i = 0; i < 8; ++i) {
            unsigned cnum = __hip_atomic_load(&CTL[1 + i], __ATOMIC_RELAXED,
                                              __HIP_MEMORY_SCOPE_AGENT);
            if (cnum > bc) { bc = cnum; best = (unsigned)i; }
        }
        int role = -1;
        if (xcc == best) {
            unsigned s = __hip_atomic_fetch_add(&CTL[9], 1u, __ATOMIC_RELAXED,
                                                __HIP_MEMORY_SCOPE_AGENT);
            if (s < NROLE) role = (int)s;
        }
        s_role = role;
    }
    __syncthreads();
    const int role = s_role;
    if (role < 0) return;

    const int ug = tid >> 5;         // 0..15 unit-in-block
    const int p  = tid & 31;         // K-part within unit
    const int j  = role * 16 + ug;   // hidden unit 0..511

    // weights for the strided K-set
    float w[4][16];
    #pragma unroll
    for (int r = 0; r < 4; ++r) {
        const float* src = Whh + (long)(r * 512 + j) * WHD + p;
        #pragma unroll
        for (int kk = 0; kk < 16; ++kk) w[r][kk] = src[kk * 32];
    }

    float c = 0.0f;
    float h16[16];
    #pragma unroll
    for (int kk = 0; kk < 16; ++kk) h16[kk] = 0.0f;

    for (int t = 0; t < N_WORDS; ++t) {
        // xp load depends only on t -> issue before the poll so latency hides
        const float4 xp = *(const float4*)(XP4 + ((long)t * WHD + j) * 4);

        if (t > 0) {
            if (tid < 64) {
                const unsigned long long* hrow =
                    (const unsigned long long*)(HS + (long)(t - 1) * WHD);
                const unsigned long long* a0 = hrow + tid;
                const unsigned long long* a1 = hrow + 64 + tid;
                const unsigned long long* a2 = hrow + 128 + tid;
                const unsigned long long* a3 = hrow + 192 + tid;
                float lo[4], hi[4];
                int it = 0;
                for (;;) {
                    unsigned long long q[4];
                    if ((++it & 7) != 0) {
                        // fast path: L1-bypass, served from the shared home L2
                        asm volatile(
                            "global_load_dwordx2 %0, %4, off sc0\n\t"
                            "global_load_dwordx2 %1, %5, off sc0\n\t"
                            "global_load_dwordx2 %2, %6, off sc0\n\t"
                            "global_load_dwordx2 %3, %7, off sc0\n\t"
                            "s_waitcnt vmcnt(0)"
                            : "=&v"(q[0]), "=&v"(q[1]), "=&v"(q[2]), "=&v"(q[3])
                            : "v"(a0), "v"(a1), "v"(a2), "v"(a3)
                            : "memory");
                    } else {
                        // insurance: the R0-proven agent-scope path (LLC) —
                        // guarantees forward progress in every semantics world
                        q[0] = __hip_atomic_load(a0, __ATOMIC_RELAXED, __HIP_MEMORY_SCOPE_AGENT);
                        q[1] = __hip_atomic_load(a1, __ATOMIC_RELAXED, __HIP_MEMORY_SCOPE_AGENT);
                        q[2] = __hip_atomic_load(a2, __ATOMIC_RELAXED, __HIP_MEMORY_SCOPE_AGENT);
                        q[3] = __hip_atomic_load(a3, __ATOMIC_RELAXED, __HIP_MEMORY_SCOPE_AGENT);
                    }
                    bool ready = true;
                    #pragma unroll
                    for (int i = 0; i < 4; ++i) {
                        lo[i] = q_lo(q[i]);
                        hi[i] = q_hi(q[i]);
                        ready = ready && (lo[i] > 0.5f) && (hi[i] > 0.5f);
                    }
                    if (ready) break;
                }
                #pragma unroll
                for (int i = 0; i < 4; ++i) {
                    hbuf[i * 128 + 2 * tid]     = lo[i] - 2.0f;
                    hbuf[i * 128 + 2 * tid + 1] = hi[i] - 2.0f;
                }
            }
            __syncthreads();
            #pragma unroll
            for (int kk = 0; kk < 16; ++kk) h16[kk] = hbuf[p + 32 * kk];
        }

        float di = 0, df = 0, dg = 0, dq = 0;
        #pragma unroll
        for (int kk = 0; kk < 16; ++kk) {
            di = fmaf(w[0][kk], h16[kk], di);
            df = fmaf(w[1][kk], h16[kk], df);
            dg = fmaf(w[2][kk], h16[kk], dg);
            dq = fmaf(w[3][kk], h16[kk], dq);
        }
        // reduce over the 32 lanes of this unit (xor masks <32 stay in each half-wave)
        #pragma unroll
        for (int m = 16; m >= 1; m >>= 1) {
            di += __shfl_xor(di, m);
            df += __shfl_xor(df, m);
            dg += __shfl_xor(dg, m);
            dq += __shfl_xor(dq, m);
        }
        float ig = fast_sigmoid(xp.x + di);
        float fg = fast_sigmoid(xp.y + df);
        float gg = fast_tanh(xp.z + dg);
        float og = fast_sigmoid(xp.w + dq);
        c = fg * c + ig * gg;
        float hn = og * fast_tanh(c);

        // dual store, same value: sc0 -> home L2 (fast path consumers poll),
        // sc1 -> LLC (agent-round insurance + post-kernel visibility).
        {
            float  hv = hn + 2.0f;
            float* hp = HS + (long)t * WHD + j;
            if (p == 0)
                asm volatile("global_store_dword %0, %1, off sc0" :: "v"(hp), "v"(hv) : "memory");
            else if (p == 1)
                asm volatile("global_store_dword %0, %1, off sc1" :: "v"(hp), "v"(hv) : "memory");
        }
        // NOTE: no trailing barrier needed. Wave 0 only overwrites hbuf for step t+1
        // after ALL 512 h[t] values are visible, which implies every wave (including
        // ours) has already consumed its step-t LDS reads.
    }
}

// ---------------- Kernel D0: transpose out_W to [512][64] for coalesced reads ----------------
__global__ void __launch_bounds__(256) transpose_outw_kernel(
    const float* __restrict__ outW, float* __restrict__ outWT)
{
    int e = blockIdx.x * 256 + threadIdx.x;  // TAG*WHD
    if (e >= TAG * WHD) return;
    int g = e >> 9, k = e & 511;
    outWT[k * TAG + g] = outW[e];
}

// ---------------- Kernel D: logits + log_softmax, one wave per word ----------------
// HS holds h+2.0 -> subtract the offset inline.
__global__ void __launch_bounds__(64) logits_kernel(
    const float* __restrict__ HS,
    const float* __restrict__ outWT,   // [512][64]
    const float* __restrict__ outb,    // [64]
    float*       __restrict__ out)     // [N, 64]
{
    int n = blockIdx.x;
    int g = threadIdx.x;
    const float* hrow = HS + (long)n * WHD;
    float acc = outb[g];
    #pragma unroll 8
    for (int k = 0; k < WHD; ++k) acc += (hrow[k] - 2.0f) * outWT[k * TAG + g];
    float m = acc;
    #pragma unroll
    for (int s = 32; s >= 1; s >>= 1) m = fmaxf(m, __shfl_xor(m, s));
    float ex = __expf(acc - m);
    float ssum = ex;
    #pragma unroll
    for (int s = 32; s >= 1; s >>= 1) ssum += __shfl_xor(ssum, s);
    out[(long)n * TAG + g] = acc - m - logf(ssum);
}

extern "C" void kernel_launch(void* const* d_in, const int* in_sizes, int n_in,
                              void* d_out, int out_size, void* d_ws, size_t ws_size,
                              hipStream_t stream)
{
    const int*   words = (const int*)   d_in[0];
    const int*   chars = (const int*)   d_in[1];
    const int*   lens  = (const int*)   d_in[2];
    const float* wemb  = (const float*) d_in[3];
    const float* cemb  = (const float*) d_in[4];
    const float* cWih  = (const float*) d_in[5];
    const float* cWhh  = (const float*) d_in[6];
    const float* cb    = (const float*) d_in[7];
    const float* wWih  = (const float*) d_in[8];
    const float* wWhh  = (const float*) d_in[9];
    const float* wb    = (const float*) d_in[10];
    const float* outW  = (const float*) d_in[11];
    const float* outb  = (const float*) d_in[12];
    float* out = (float*)d_out;

    // workspace layout (bytes)
    char* ws = (char*)d_ws;
    size_t off = 0;
    float*    h_char = (float*)(ws + off); off += (size_t)N_WORDS * CHD * 4;   // 196,608
    float*    X      = (float*)(ws + off); off += (size_t)N_WORDS * XDIM * 4;  // 16.8 MB
    float*    XP4    = (float*)(ws + off); off += (size_t)N_WORDS * G4 * 4;    // 67.1 MB
    float*    HS     = (float*)(ws + off); off += (size_t)N_WORDS * WHD * 4;   // 16.8 MB
    float*    outWT  = (float*)(ws + off); off += (size_t)WHD * TAG * 4;       // 128 KB
    unsigned* CTL    = (unsigned*)(ws + off); off += 16 * sizeof(unsigned);    // 64 B

    // HS must be zero so the sentinel protocol (stored h+2 > 0.5) is well-defined.
    hipMemsetAsync(HS, 0, (size_t)N_WORDS * WHD * sizeof(float), stream);
    // CTL must be zero for the election (arrival barrier, counters, claims).
    hipMemsetAsync(CTL, 0, 16 * sizeof(unsigned), stream);

    char_lstm_kernel<<<N_WORDS / 256, 256, 0, stream>>>(chars, lens, cemb, cWih, cWhh, cb, h_char);
    build_x_kernel<<<(N_WORDS * XDIM) / 256, 256, 0, stream>>>(words, wemb, h_char, X);
    xp_gemm_kernel<<<(N_WORDS / BM) * (G4 / BN), 256, 0, stream>>>(X, wWih, wb, XP4);
    transpose_outw_kernel<<<(TAG * WHD) / 256, 256, 0, stream>>>(outW, outWT);
    word_lstm_kernel<<<NBLK, 512, 0, stream>>>(wWhh, XP4, HS, CTL);
    logits_kernel<<<N_WORDS, 64, 0, stream>>>(HS, outWT, outb, out);
}

// Round 8
// 16408.307 us; speedup vs baseline: 2.6342x; 2.6342x over previous
//
#include <hip/hip_runtime.h>
#include <hip/hip_bf16.h>
#include <math.h>

#define N_WORDS 8192
#define LMAX    16
#define WED     506
#define WHD     512
#define CED     6
#define CHD     6
#define CVOC    128
#define TAG     64
#define XDIM    512      // WED + CHD
#define G4      2048     // 4*WHD
#define NWG     32       // workgroups for the word LSTM (16 units each)

__device__ __forceinline__ float fast_sigmoid(float x) { return 1.0f / (1.0f + __expf(-x)); }
__device__ __forceinline__ float fast_tanh(float x)    { return 2.0f / (1.0f + __expf(-2.0f * x)) - 1.0f; }

// ---------------- Kernel A: char-level LSTM, one thread per word ----------------
__global__ void __launch_bounds__(256) char_lstm_kernel(
    const int*   __restrict__ chars,     // [N, LMAX]
    const int*   __restrict__ lens,      // [N]
    const float* __restrict__ char_emb,  // [CVOC, CED]
    const float* __restrict__ cWih,      // [24, 6]
    const float* __restrict__ cWhh,      // [24, 6]
    const float* __restrict__ cb,        // [24]
    float*       __restrict__ h_char)    // [N, CHD]
{
    __shared__ float sWih[24][6], sWhh[24][6], sb[24], semb[CVOC][CED];
    int t = threadIdx.x;
    if (t < 144) { sWih[t / 6][t % 6] = cWih[t]; sWhh[t / 6][t % 6] = cWhh[t]; }
    if (t < 24) sb[t] = cb[t];
    for (int i = t; i < CVOC * CED; i += 256) semb[i / CED][i % CED] = char_emb[i];
    __syncthreads();

    int n = blockIdx.x * 256 + t;
    if (n >= N_WORDS) return;
    int len = lens[n];
    float h[CHD] = {0, 0, 0, 0, 0, 0};
    float c[CHD] = {0, 0, 0, 0, 0, 0};
    for (int l = 0; l < LMAX; ++l) {
        if (l >= len) break;  // once l >= len no further state updates occur
        int ch = chars[n * LMAX + l];
        float e[CED];
        #pragma unroll
        for (int k = 0; k < CED; ++k) e[k] = semb[ch][k];
        float pre[24];
        #pragma unroll
        for (int g = 0; g < 24; ++g) {
            float a = sb[g];
            #pragma unroll
            for (int k = 0; k < CED; ++k) a += e[k] * sWih[g][k];
            #pragma unroll
            for (int k = 0; k < CHD; ++k) a += h[k] * sWhh[g][k];
            pre[g] = a;
        }
        #pragma unroll
        for (int u = 0; u < CHD; ++u) {
            float ig = fast_sigmoid(pre[u]);
            float fg = fast_sigmoid(pre[6 + u]);
            float gg = fast_tanh(pre[12 + u]);
            float og = fast_sigmoid(pre[18 + u]);
            float cn = fg * c[u] + ig * gg;
            c[u] = cn;
            h[u] = og * fast_tanh(cn);
        }
    }
    for (int u = 0; u < CHD; ++u) h_char[n * CHD + u] = h[u];
}

// ---------------- Kernel B0: X = [word_emb gather | h_char] ----------------
__global__ void __launch_bounds__(256) build_x_kernel(
    const int*   __restrict__ words,
    const float* __restrict__ word_emb,  // [WV, WED]
    const float* __restrict__ h_char,    // [N, CHD]
    float*       __restrict__ X)         // [N, XDIM]
{
    long idx = (long)blockIdx.x * 256 + threadIdx.x;
    if (idx >= (long)N_WORDS * XDIM) return;
    int n = (int)(idx >> 9), k = (int)(idx & 511);
    float v;
    if (k < WED) v = word_emb[(long)words[n] * WED + k];
    else         v = h_char[n * CHD + (k - WED)];
    X[idx] = v;
}

// ---------------- Kernel B1: XP4 = X @ Wih^T + b, fp32 tiled GEMM ----------------
// Epilogue writes gate-interleaved layout XP4[t][unit][gate] so the word LSTM
// reads one float4 per thread per step.
#define BM 64
#define BN 64
#define BK 16
__global__ void __launch_bounds__(256) xp_gemm_kernel(
    const float* __restrict__ X,    // [N, 512]
    const float* __restrict__ Wih,  // [2048, 512]
    const float* __restrict__ wb,   // [2048]
    float*       __restrict__ XP4)  // [N, 512, 4]
{
    __shared__ float As[BM][BK + 1];
    __shared__ float Bs[BN][BK + 1];
    int tid = threadIdx.x;
    int bm = (blockIdx.x % (N_WORDS / BM)) * BM;
    int bn = (blockIdx.x / (N_WORDS / BM)) * BN;
    int ty = tid / 16, tx = tid % 16;
    float acc[4][4] = {};
    for (int k0 = 0; k0 < XDIM; k0 += BK) {
        #pragma unroll
        for (int i = 0; i < 4; ++i) {
            int e = tid + i * 256;
            int r = e >> 4, cc = e & 15;
            As[r][cc] = X[(long)(bm + r) * XDIM + k0 + cc];
            Bs[r][cc] = Wih[(long)(bn + r) * XDIM + k0 + cc];
        }
        __syncthreads();
        #pragma unroll
        for (int kk = 0; kk < BK; ++kk) {
            float a[4], b[4];
            #pragma unroll
            for (int i = 0; i < 4; ++i) a[i] = As[ty * 4 + i][kk];
            #pragma unroll
            for (int j = 0; j < 4; ++j) b[j] = Bs[tx * 4 + j][kk];
            #pragma unroll
            for (int i = 0; i < 4; ++i)
                #pragma unroll
                for (int j = 0; j < 4; ++j) acc[i][j] += a[i] * b[j];
        }
        __syncthreads();
    }
    #pragma unroll
    for (int i = 0; i < 4; ++i) {
        int m = bm + ty * 4 + i;
        #pragma unroll
        for (int j = 0; j < 4; ++j) {
            int g = bn + tx * 4 + j;
            int unit = g & 511, gate = g >> 9;
            XP4[((long)m * WHD + unit) * 4 + gate] = acc[i][j] + wb[g];
        }
    }
}

// ---------------- Kernel C: sequential word LSTM (R0 structure, low-contention) ----
// 32 WGs x 512 threads. WG wg owns units [wg*16, wg*16+16); lane p of unit ug owns
// the strided K-set {p + 32*kk} — per-thread inner loop identical to the proven R0.
// Sentinel protocol unchanged from R0: HS[t][u] written once as h+2.0 (in [1,3]);
// HS pre-zeroed; ready <=> v > 0.5; agent-scope (LLC) loads/stores ONLY (the one
// transport proven correct+fast across R0-R6).
// Contention fixes vs R0 (both attack LLC queueing / straggler spread):
//  (a) 32 pollers instead of 64 (halves poll packets and the max-of-N straggler N);
//  (b) ONE coalesced 64B store per WG per step (LDS gather + lanes 0..15),
//      replacing 8 scattered 4B stores -> 512->32 store packets/step.
__global__ void __launch_bounds__(512, 1) word_lstm_kernel(
    const float* __restrict__ Whh,  // [2048, 512]
    const float* __restrict__ XP4,  // [N, 512, 4] gate-interleaved
    float*       HS)                // [N, 512]; stores h+2.0; pre-zeroed
{
    __shared__ float hbuf[WHD];     // h[t-1] (offset removed)
    __shared__ float hstage[16];    // this WG's 16 fresh h values (with +2 offset)

    const int tid = threadIdx.x;
    const int wg  = blockIdx.x;      // 0..31
    const int ug  = tid >> 5;        // 0..15 unit-in-block
    const int p   = tid & 31;        // K-part within unit
    const int j   = wg * 16 + ug;    // hidden unit 0..511

    // weights for the strided K-set
    float w[4][16];
    #pragma unroll
    for (int r = 0; r < 4; ++r) {
        const float* src = Whh + (long)(r * 512 + j) * WHD + p;
        #pragma unroll
        for (int kk = 0; kk < 16; ++kk) w[r][kk] = src[kk * 32];
    }

    float c = 0.0f;
    float h16[16];
    #pragma unroll
    for (int kk = 0; kk < 16; ++kk) h16[kk] = 0.0f;

    for (int t = 0; t < N_WORDS; ++t) {
        // xp load depends only on t -> issue before the poll so HBM latency hides
        const float4 xp = *(const float4*)(XP4 + ((long)t * WHD + j) * 4);

        if (t > 0) {
            if (tid < 64) {
                // wave 0 polls the full h[t-1] row: 8 x u64 loads (16 lines), as R0
                const unsigned long long* hrow =
                    (const unsigned long long*)(HS + (long)(t - 1) * WHD);
                float lo[4], hi[4];
                bool ready = false;
                while (!ready) {
                    unsigned long long q[4];
                    #pragma unroll
                    for (int i = 0; i < 4; ++i)
                        q[i] = __hip_atomic_load(&hrow[i * 64 + tid], __ATOMIC_RELAXED,
                                                 __HIP_MEMORY_SCOPE_AGENT);
                    ready = true;
                    #pragma unroll
                    for (int i = 0; i < 4; ++i) {
                        lo[i] = __uint_as_float((unsigned)(q[i] & 0xffffffffu));
                        hi[i] = __uint_as_float((unsigned)(q[i] >> 32));
                        ready = ready && (lo[i] > 0.5f) && (hi[i] > 0.5f);
                    }
                }
                #pragma unroll
                for (int i = 0; i < 4; ++i) {
                    hbuf[i * 128 + 2 * tid]     = lo[i] - 2.0f;
                    hbuf[i * 128 + 2 * tid + 1] = hi[i] - 2.0f;
                }
            }
            __syncthreads();
            #pragma unroll
            for (int kk = 0; kk < 16; ++kk) h16[kk] = hbuf[p + 32 * kk];
        }

        float di = 0, df = 0, dg = 0, dq = 0;
        #pragma unroll
        for (int kk = 0; kk < 16; ++kk) {
            di = fmaf(w[0][kk], h16[kk], di);
            df = fmaf(w[1][kk], h16[kk], df);
            dg = fmaf(w[2][kk], h16[kk], dg);
            dq = fmaf(w[3][kk], h16[kk], dq);
        }
        // reduce over the 32 lanes of this unit (xor masks <32 stay in each half-wave)
        #pragma unroll
        for (int m = 16; m >= 1; m >>= 1) {
            di += __shfl_xor(di, m);
            df += __shfl_xor(df, m);
            dg += __shfl_xor(dg, m);
            dq += __shfl_xor(dq, m);
        }
        float ig = fast_sigmoid(xp.x + di);
        float fg = fast_sigmoid(xp.y + df);
        float gg = fast_tanh(xp.z + dg);
        float og = fast_sigmoid(xp.w + dq);
        c = fg * c + ig * gg;
        float hn = og * fast_tanh(c);

        // gather the WG's 16 h values in LDS, then ONE coalesced 64B store
        if (p == 0) hstage[ug] = hn + 2.0f;
        __syncthreads();
        if (tid < 16)
            __hip_atomic_store(&HS[(long)t * WHD + wg * 16 + tid], hstage[tid],
                               __ATOMIC_RELAXED, __HIP_MEMORY_SCOPE_AGENT);
        // hstage reuse safety: tid<16 read hstage here (before entering step t+1's
        // poll); the next writes to hstage (p==0 threads at t+1) happen only after
        // the t+1 poll barrier, which all threads pass -> read < barrier < write.
        // hbuf reuse safety: unchanged R0 argument (wave 0 overwrites hbuf for
        // t+1 only after the full row t is LLC-visible, implying every wave in
        // every WG consumed its step-t LDS reads).
    }
}

// ---------------- Kernel D0: transpose out_W to [512][64] for coalesced reads ----------------
__global__ void __launch_bounds__(256) transpose_outw_kernel(
    const float* __restrict__ outW, float* __restrict__ outWT)
{
    int e = blockIdx.x * 256 + threadIdx.x;  // TAG*WHD
    if (e >= TAG * WHD) return;
    int g = e >> 9, k = e & 511;
    outWT[k * TAG + g] = outW[e];
}

// ---------------- Kernel D: logits + log_softmax, one wave per word ----------------
// HS holds h+2.0 -> subtract the offset inline.
__global__ void __launch_bounds__(64) logits_kernel(
    const float* __restrict__ HS,
    const float* __restrict__ outWT,   // [512][64]
    const float* __restrict__ outb,    // [64]
    float*       __restrict__ out)     // [N, 64]
{
    int n = blockIdx.x;
    int g = threadIdx.x;
    const float* hrow = HS + (long)n * WHD;
    float acc = outb[g];
    #pragma unroll 8
    for (int k = 0; k < WHD; ++k) acc += (hrow[k] - 2.0f) * outWT[k * TAG + g];
    float m = acc;
    #pragma unroll
    for (int s = 32; s >= 1; s >>= 1) m = fmaxf(m, __shfl_xor(m, s));
    float ex = __expf(acc - m);
    float ssum = ex;
    #pragma unroll
    for (int s = 32; s >= 1; s >>= 1) ssum += __shfl_xor(ssum, s);
    out[(long)n * TAG + g] = acc - m - logf(ssum);
}

extern "C" void kernel_launch(void* const* d_in, const int* in_sizes, int n_in,
                              void* d_out, int out_size, void* d_ws, size_t ws_size,
                              hipStream_t stream)
{
    const int*   words = (const int*)   d_in[0];
    const int*   chars = (const int*)   d_in[1];
    const int*   lens  = (const int*)   d_in[2];
    const float* wemb  = (const float*) d_in[3];
    const float* cemb  = (const float*) d_in[4];
    const float* cWih  = (const float*) d_in[5];
    const float* cWhh  = (const float*) d_in[6];
    const float* cb    = (const float*) d_in[7];
    const float* wWih  = (const float*) d_in[8];
    const float* wWhh  = (const float*) d_in[9];
    const float* wb    = (const float*) d_in[10];
    const float* outW  = (const float*) d_in[11];
    const float* outb  = (const float*) d_in[12];
    float* out = (float*)d_out;

    // workspace layout (bytes)
    char* ws = (char*)d_ws;
    size_t off = 0;
    float* h_char = (float*)(ws + off); off += (size_t)N_WORDS * CHD * 4;      // 196,608
    float* X      = (float*)(ws + off); off += (size_t)N_WORDS * XDIM * 4;     // 16.8 MB
    float* XP4    = (float*)(ws + off); off += (size_t)N_WORDS * G4 * 4;       // 67.1 MB
    float* HS     = (float*)(ws + off); off += (size_t)N_WORDS * WHD * 4;      // 16.8 MB
    float* outWT  = (float*)(ws + off); off += (size_t)WHD * TAG * 4;          // 128 KB

    // HS must be zero so the sentinel protocol (stored h+2 > 0.5) is well-defined.
    hipMemsetAsync(HS, 0, (size_t)N_WORDS * WHD * sizeof(float), stream);

    char_lstm_kernel<<<N_WORDS / 256, 256, 0, stream>>>(chars, lens, cemb, cWih, cWhh, cb, h_char);
    build_x_kernel<<<(N_WORDS * XDIM) / 256, 256, 0, stream>>>(words, wemb, h_char, X);
    xp_gemm_kernel<<<(N_WORDS / BM) * (G4 / BN), 256, 0, stream>>>(X, wWih, wb, XP4);
    transpose_outw_kernel<<<(TAG * WHD) / 256, 256, 0, stream>>>(outW, outWT);
    word_lstm_kernel<<<NWG, 512, 0, stream>>>(wWhh, XP4, HS);
    logits_kernel<<<N_WORDS, 64, 0, stream>>>(HS, outWT, outb, out);
}

// Round 9
// 16204.216 us; speedup vs baseline: 2.6674x; 1.0126x over previous
//
#include <hip/hip_runtime.h>
#include <hip/hip_bf16.h>
#include <math.h>

#define N_WORDS 8192
#define LMAX    16
#define WED     506
#define WHD     512
#define CED     6
#define CHD     6
#define CVOC    128
#define TAG     64
#define XDIM    512      // WED + CHD
#define G4      2048     // 4*WHD
#define NWG     32       // workgroups for the word LSTM (16 units each)

__device__ __forceinline__ float fast_sigmoid(float x) { return 1.0f / (1.0f + __expf(-x)); }
__device__ __forceinline__ float fast_tanh(float x)    { return 2.0f / (1.0f + __expf(-2.0f * x)) - 1.0f; }

__device__ __forceinline__ bool rdy8(unsigned long long q0, unsigned long long q1,
                                     unsigned long long q2, unsigned long long q3) {
    float l0 = __uint_as_float((unsigned)(q0 & 0xffffffffu));
    float h0 = __uint_as_float((unsigned)(q0 >> 32));
    float l1 = __uint_as_float((unsigned)(q1 & 0xffffffffu));
    float h1 = __uint_as_float((unsigned)(q1 >> 32));
    float l2 = __uint_as_float((unsigned)(q2 & 0xffffffffu));
    float h2 = __uint_as_float((unsigned)(q2 >> 32));
    float l3 = __uint_as_float((unsigned)(q3 & 0xffffffffu));
    float h3 = __uint_as_float((unsigned)(q3 >> 32));
    float m = fminf(fminf(fminf(l0, h0), fminf(l1, h1)),
                    fminf(fminf(l2, h2), fminf(l3, h3)));
    return m > 0.5f;
}

// ---------------- Kernel A: char-level LSTM, one thread per word ----------------
__global__ void __launch_bounds__(256) char_lstm_kernel(
    const int*   __restrict__ chars,     // [N, LMAX]
    const int*   __restrict__ lens,      // [N]
    const float* __restrict__ char_emb,  // [CVOC, CED]
    const float* __restrict__ cWih,      // [24, 6]
    const float* __restrict__ cWhh,      // [24, 6]
    const float* __restrict__ cb,        // [24]
    float*       __restrict__ h_char)    // [N, CHD]
{
    __shared__ float sWih[24][6], sWhh[24][6], sb[24], semb[CVOC][CED];
    int t = threadIdx.x;
    if (t < 144) { sWih[t / 6][t % 6] = cWih[t]; sWhh[t / 6][t % 6] = cWhh[t]; }
    if (t < 24) sb[t] = cb[t];
    for (int i = t; i < CVOC * CED; i += 256) semb[i / CED][i % CED] = char_emb[i];
    __syncthreads();

    int n = blockIdx.x * 256 + t;
    if (n >= N_WORDS) return;
    int len = lens[n];
    float h[CHD] = {0, 0, 0, 0, 0, 0};
    float c[CHD] = {0, 0, 0, 0, 0, 0};
    for (int l = 0; l < LMAX; ++l) {
        if (l >= len) break;  // once l >= len no further state updates occur
        int ch = chars[n * LMAX + l];
        float e[CED];
        #pragma unroll
        for (int k = 0; k < CED; ++k) e[k] = semb[ch][k];
        float pre[24];
        #pragma unroll
        for (int g = 0; g < 24; ++g) {
            float a = sb[g];
            #pragma unroll
            for (int k = 0; k < CED; ++k) a += e[k] * sWih[g][k];
            #pragma unroll
            for (int k = 0; k < CHD; ++k) a += h[k] * sWhh[g][k];
            pre[g] = a;
        }
        #pragma unroll
        for (int u = 0; u < CHD; ++u) {
            float ig = fast_sigmoid(pre[u]);
            float fg = fast_sigmoid(pre[6 + u]);
            float gg = fast_tanh(pre[12 + u]);
            float og = fast_sigmoid(pre[18 + u]);
            float cn = fg * c[u] + ig * gg;
            c[u] = cn;
            h[u] = og * fast_tanh(cn);
        }
    }
    for (int u = 0; u < CHD; ++u) h_char[n * CHD + u] = h[u];
}

// ---------------- Kernel B0: X = [word_emb gather | h_char] ----------------
__global__ void __launch_bounds__(256) build_x_kernel(
    const int*   __restrict__ words,
    const float* __restrict__ word_emb,  // [WV, WED]
    const float* __restrict__ h_char,    // [N, CHD]
    float*       __restrict__ X)         // [N, XDIM]
{
    long idx = (long)blockIdx.x * 256 + threadIdx.x;
    if (idx >= (long)N_WORDS * XDIM) return;
    int n = (int)(idx >> 9), k = (int)(idx & 511);
    float v;
    if (k < WED) v = word_emb[(long)words[n] * WED + k];
    else         v = h_char[n * CHD + (k - WED)];
    X[idx] = v;
}

// ---------------- Kernel B1: XP4 = X @ Wih^T + b, fp32 tiled GEMM ----------------
// Epilogue writes gate-interleaved layout XP4[t][unit][gate] so the word LSTM
// reads one float4 per thread per step.
#define BM 64
#define BN 64
#define BK 16
__global__ void __launch_bounds__(256) xp_gemm_kernel(
    const float* __restrict__ X,    // [N, 512]
    const float* __restrict__ Wih,  // [2048, 512]
    const float* __restrict__ wb,   // [2048]
    float*       __restrict__ XP4)  // [N, 512, 4]
{
    __shared__ float As[BM][BK + 1];
    __shared__ float Bs[BN][BK + 1];
    int tid = threadIdx.x;
    int bm = (blockIdx.x % (N_WORDS / BM)) * BM;
    int bn = (blockIdx.x / (N_WORDS / BM)) * BN;
    int ty = tid / 16, tx = tid % 16;
    float acc[4][4] = {};
    for (int k0 = 0; k0 < XDIM; k0 += BK) {
        #pragma unroll
        for (int i = 0; i < 4; ++i) {
            int e = tid + i * 256;
            int r = e >> 4, cc = e & 15;
            As[r][cc] = X[(long)(bm + r) * XDIM + k0 + cc];
            Bs[r][cc] = Wih[(long)(bn + r) * XDIM + k0 + cc];
        }
        __syncthreads();
        #pragma unroll
        for (int kk = 0; kk < BK; ++kk) {
            float a[4], b[4];
            #pragma unroll
            for (int i = 0; i < 4; ++i) a[i] = As[ty * 4 + i][kk];
            #pragma unroll
            for (int j = 0; j < 4; ++j) b[j] = Bs[tx * 4 + j][kk];
            #pragma unroll
            for (int i = 0; i < 4; ++i)
                #pragma unroll
                for (int j = 0; j < 4; ++j) acc[i][j] += a[i] * b[j];
        }
        __syncthreads();
    }
    #pragma unroll
    for (int i = 0; i < 4; ++i) {
        int m = bm + ty * 4 + i;
        #pragma unroll
        for (int j = 0; j < 4; ++j) {
            int g = bn + tx * 4 + j;
            int unit = g & 511, gate = g >> 9;
            XP4[((long)m * WHD + unit) * 4 + gate] = acc[i][j] + wb[g];
        }
    }
}

// ---------------- Kernel C: sequential word LSTM (R8 structure + 2-deep poll) ------
// 32 WGs x 512 threads. WG wg owns units [wg*16, wg*16+16); lane p of unit ug owns
// the strided K-set {p + 32*kk}. Sentinel protocol: HS[t][u] written once as h+2.0
// (in [1,3]); HS pre-zeroed; ready <=> v > 0.5; agent-scope (LLC) transport only.
// Retained from R8 (proven -10%): 32 pollers; ONE coalesced 64B store per WG
// (LDS gather + lanes 0..15). NEW this round (the single variable under test):
// the poller keeps TWO 8-load rounds in flight. Checking round A while round B is
// outstanding compiles to a partial vmcnt wait, so the sampling period becomes the
// check+reissue time (~60cy) instead of a full LLC RTT (~600cy) — collapsing the
// uniform(0,RTT) detect-phase term whose max-over-32-WGs was ~500cy of every step.
__global__ void __launch_bounds__(512, 1) word_lstm_kernel(
    const float* __restrict__ Whh,  // [2048, 512]
    const float* __restrict__ XP4,  // [N, 512, 4] gate-interleaved
    float*       HS)                // [N, 512]; stores h+2.0; pre-zeroed
{
    __shared__ float hbuf[WHD];     // h[t-1] (offset removed)
    __shared__ float hstage[16];    // this WG's 16 fresh h values (with +2 offset)

    const int tid = threadIdx.x;
    const int wg  = blockIdx.x;      // 0..31
    const int ug  = tid >> 5;        // 0..15 unit-in-block
    const int p   = tid & 31;        // K-part within unit
    const int j   = wg * 16 + ug;    // hidden unit 0..511

    // weights for the strided K-set
    float w[4][16];
    #pragma unroll
    for (int r = 0; r < 4; ++r) {
        const float* src = Whh + (long)(r * 512 + j) * WHD + p;
        #pragma unroll
        for (int kk = 0; kk < 16; ++kk) w[r][kk] = src[kk * 32];
    }

    float c = 0.0f;
    float h16[16];
    #pragma unroll
    for (int kk = 0; kk < 16; ++kk) h16[kk] = 0.0f;

    for (int t = 0; t < N_WORDS; ++t) {
        // xp load depends only on t -> issue before the poll so HBM latency hides
        const float4 xp = *(const float4*)(XP4 + ((long)t * WHD + j) * 4);

        if (t > 0) {
            if (tid < 64) {
                // wave 0 polls the full h[t-1] row: 8 x u64 per lane (16 lines),
                // 2-deep pipelined (rounds A and B alternate; one always in flight)
                const unsigned long long* hrow =
                    (const unsigned long long*)(HS + (long)(t - 1) * WHD);
                #define LDQ(i) __hip_atomic_load(&hrow[(i) * 64 + tid], \
                                __ATOMIC_RELAXED, __HIP_MEMORY_SCOPE_AGENT)
                unsigned long long a0, a1, a2, a3, b0, b1, b2, b3;
                unsigned long long q0, q1, q2, q3;
                a0 = LDQ(0); a1 = LDQ(1); a2 = LDQ(2); a3 = LDQ(3);
                b0 = LDQ(0); b1 = LDQ(1); b2 = LDQ(2); b3 = LDQ(3);
                for (;;) {
                    // checking A waits only for A (B stays in flight: vmcnt(4))
                    if (rdy8(a0, a1, a2, a3)) { q0 = a0; q1 = a1; q2 = a2; q3 = a3; break; }
                    a0 = LDQ(0); a1 = LDQ(1); a2 = LDQ(2); a3 = LDQ(3);
                    if (rdy8(b0, b1, b2, b3)) { q0 = b0; q1 = b1; q2 = b2; q3 = b3; break; }
                    b0 = LDQ(0); b1 = LDQ(1); b2 = LDQ(2); b3 = LDQ(3);
                }
                #undef LDQ
                #pragma unroll
                for (int i = 0; i < 4; ++i) {
                    unsigned long long qq = (i == 0) ? q0 : (i == 1) ? q1 : (i == 2) ? q2 : q3;
                    float lo = __uint_as_float((unsigned)(qq & 0xffffffffu));
                    float hi = __uint_as_float((unsigned)(qq >> 32));
                    hbuf[i * 128 + 2 * tid]     = lo - 2.0f;
                    hbuf[i * 128 + 2 * tid + 1] = hi - 2.0f;
                }
            }
            __syncthreads();
            #pragma unroll
            for (int kk = 0; kk < 16; ++kk) h16[kk] = hbuf[p + 32 * kk];
        }

        float di = 0, df = 0, dg = 0, dq = 0;
        #pragma unroll
        for (int kk = 0; kk < 16; ++kk) {
            di = fmaf(w[0][kk], h16[kk], di);
            df = fmaf(w[1][kk], h16[kk], df);
            dg = fmaf(w[2][kk], h16[kk], dg);
            dq = fmaf(w[3][kk], h16[kk], dq);
        }
        // reduce over the 32 lanes of this unit (xor masks <32 stay in each half-wave)
        #pragma unroll
        for (int m = 16; m >= 1; m >>= 1) {
            di += __shfl_xor(di, m);
            df += __shfl_xor(df, m);
            dg += __shfl_xor(dg, m);
            dq += __shfl_xor(dq, m);
        }
        float ig = fast_sigmoid(xp.x + di);
        float fg = fast_sigmoid(xp.y + df);
        float gg = fast_tanh(xp.z + dg);
        float og = fast_sigmoid(xp.w + dq);
        c = fg * c + ig * gg;
        float hn = og * fast_tanh(c);

        // gather the WG's 16 h values in LDS, then ONE coalesced 64B store
        if (p == 0) hstage[ug] = hn + 2.0f;
        __syncthreads();
        if (tid < 16)
            __hip_atomic_store(&HS[(long)t * WHD + wg * 16 + tid], hstage[tid],
                               __ATOMIC_RELAXED, __HIP_MEMORY_SCOPE_AGENT);
        // hstage reuse safety: tid<16 read hstage here (before entering step t+1's
        // poll); the next writes to hstage (p==0 threads at t+1) happen only after
        // the t+1 poll barrier, which all threads pass -> read < barrier < write.
        // hbuf reuse safety: unchanged R0 argument (wave 0 overwrites hbuf for
        // t+1 only after the full row t is LLC-visible, implying every wave in
        // every WG consumed its step-t LDS reads).
    }
}

// ---------------- Kernel D0: transpose out_W to [512][64] for coalesced reads ----------------
__global__ void __launch_bounds__(256) transpose_outw_kernel(
    const float* __restrict__ outW, float* __restrict__ outWT)
{
    int e = blockIdx.x * 256 + threadIdx.x;  // TAG*WHD
    if (e >= TAG * WHD) return;
    int g = e >> 9, k = e & 511;
    outWT[k * TAG + g] = outW[e];
}

// ---------------- Kernel D: logits + log_softmax, one wave per word ----------------
// HS holds h+2.0 -> subtract the offset inline.
__global__ void __launch_bounds__(64) logits_kernel(
    const float* __restrict__ HS,
    const float* __restrict__ outWT,   // [512][64]
    const float* __restrict__ outb,    // [64]
    float*       __restrict__ out)     // [N, 64]
{
    int n = blockIdx.x;
    int g = threadIdx.x;
    const float* hrow = HS + (long)n * WHD;
    float acc = outb[g];
    #pragma unroll 8
    for (int k = 0; k < WHD; ++k) acc += (hrow[k] - 2.0f) * outWT[k * TAG + g];
    float m = acc;
    #pragma unroll
    for (int s = 32; s >= 1; s >>= 1) m = fmaxf(m, __shfl_xor(m, s));
    float ex = __expf(acc - m);
    float ssum = ex;
    #pragma unroll
    for (int s = 32; s >= 1; s >>= 1) ssum += __shfl_xor(ssum, s);
    out[(long)n * TAG + g] = acc - m - logf(ssum);
}

extern "C" void kernel_launch(void* const* d_in, const int* in_sizes, int n_in,
                              void* d_out, int out_size, void* d_ws, size_t ws_size,
                              hipStream_t stream)
{
    const int*   words = (const int*)   d_in[0];
    const int*   chars = (const int*)   d_in[1];
    const int*   lens  = (const int*)   d_in[2];
    const float* wemb  = (const float*) d_in[3];
    const float* cemb  = (const float*) d_in[4];
    const float* cWih  = (const float*) d_in[5];
    const float* cWhh  = (const float*) d_in[6];
    const float* cb    = (const float*) d_in[7];
    const float* wWih  = (const float*) d_in[8];
    const float* wWhh  = (const float*) d_in[9];
    const float* wb    = (const float*) d_in[10];
    const float* outW  = (const float*) d_in[11];
    const float* outb  = (const float*) d_in[12];
    float* out = (float*)d_out;

    // workspace layout (bytes)
    char* ws = (char*)d_ws;
    size_t off = 0;
    float* h_char = (float*)(ws + off); off += (size_t)N_WORDS * CHD * 4;      // 196,608
    float* X      = (float*)(ws + off); off += (size_t)N_WORDS * XDIM * 4;     // 16.8 MB
    float* XP4    = (float*)(ws + off); off += (size_t)N_WORDS * G4 * 4;       // 67.1 MB
    float* HS     = (float*)(ws + off); off += (size_t)N_WORDS * WHD * 4;      // 16.8 MB
    float* outWT  = (float*)(ws + off); off += (size_t)WHD * TAG * 4;          // 128 KB

    // HS must be zero so the sentinel protocol (stored h+2 > 0.5) is well-defined.
    hipMemsetAsync(HS, 0, (size_t)N_WORDS * WHD * sizeof(float), stream);

    char_lstm_kernel<<<N_WORDS / 256, 256, 0, stream>>>(chars, lens, cemb, cWih, cWhh, cb, h_char);
    build_x_kernel<<<(N_WORDS * XDIM) / 256, 256, 0, stream>>>(words, wemb, h_char, X);
    xp_gemm_kernel<<<(N_WORDS / BM) * (G4 / BN), 256, 0, stream>>>(X, wWih, wb, XP4);
    transpose_outw_kernel<<<(TAG * WHD) / 256, 256, 0, stream>>>(outW, outWT);
    word_lstm_kernel<<<NWG, 512, 0, stream>>>(wWhh, XP4, HS);
    logits_kernel<<<N_WORDS, 64, 0, stream>>>(HS, outWT, outb, out);
}